// Round 2
// baseline (113.254 us; speedup 1.0000x reference)
//
#include <hip/hip_runtime.h>

#define NQ 12
#define DIM 4096          // 2^12 amplitudes
#define DEPTH 4
#define BLK 256

// inverse Gray code on 12 bits: bit p of result = XOR of bits >= p of v.
// This is the whole CNOT chain CNOT(0,1)...CNOT(10,11) as one permutation:
// new_state[igray12(src)] = old_state[src]. Linear over GF(2).
__device__ __forceinline__ int igray12(int v) {
    v ^= v >> 1;
    v ^= v >> 2;
    v ^= v >> 4;
    v ^= v >> 8;
    return v & (DIM - 1);
}

// RY gate on local subcube bit PB (compile-time => all register indices static)
template<int PB>
__device__ __forceinline__ void apply_gate(float2 (&a)[16], float c, float s) {
    #pragma unroll
    for (int j0 = 0; j0 < 16; ++j0) {
        if (j0 & PB) continue;
        const int j1 = j0 | PB;
        float2 a0 = a[j0], a1 = a[j1];
        a[j0] = make_float2(c * a0.x - s * a1.x, c * a0.y - s * a1.y);
        a[j1] = make_float2(s * a0.x + c * a1.x, s * a0.y + c * a1.y);
    }
}

__global__ __launch_bounds__(BLK, 2)
void qsim_kernel(const float* __restrict__ x,
                 const float* __restrict__ rys,
                 float* __restrict__ out) {
    __shared__ __align__(16) float2 buf[DIM];        // 32 KB state
    __shared__ float cr[DEPTH * NQ], sr[DEPTH * NQ]; // RY cos/sin (shared)
    __shared__ float cxs[NQ], sxs[NQ];               // RX cos/sin (per batch)
    __shared__ float zred[4][NQ];

    const int b = blockIdx.x;
    const int t = threadIdx.x;

    if (t < DEPTH * NQ) {
        float th = 0.5f * rys[t];
        cr[t] = cosf(th);
        sr[t] = sinf(th);
    } else if (t >= 64 && t < 64 + NQ) {
        int q = t - 64;
        float th = 0.5f * x[b * NQ + q];
        cxs[q] = cosf(th);
        sxs[q] = sinf(th);
    }
    __syncthreads();

    float2 a[16];                       // the thread's 16 amplitudes
    float4* buf4 = reinterpret_cast<float4*>(buf);
    const int rot = t & 7;              // sweep-1 chunk rotation (bank spread)

    // ---- initial product state, built directly in sweep-1 layout ----
    // m = (t<<4) | j ; amp(m) = prod_p(bit_p ? sin : cos)[qubit 11-p] * (-i)^popc(m)
    {
        float base = 1.0f;
        #pragma unroll
        for (int p = 4; p < NQ; ++p)
            base *= ((t >> (p - 4)) & 1) ? sxs[NQ - 1 - p] : cxs[NQ - 1 - p];
        const int pch = __popc(t);
        #pragma unroll
        for (int j = 0; j < 16; ++j) {
            float mag = base;
            #pragma unroll
            for (int p = 0; p < 4; ++p)
                mag *= ((j >> p) & 1) ? sxs[NQ - 1 - p] : cxs[NQ - 1 - p];
            int pc = (pch + __popc(j)) & 3;
            float2 v;
            v.x = (pc == 0) ? mag : ((pc == 2) ? -mag : 0.0f);
            v.y = (pc == 1) ? -mag : ((pc == 3) ? mag : 0.0f);
            a[j] = v;
        }
    }

    for (int d = 0; d < DEPTH; ++d) {
        const int cb = d * NQ;
        // ---- sweep 1: gates on bits p=0..3 (qubits 11..8) ----
        if (d > 0) {
            #pragma unroll
            for (int c = 0; c < 8; ++c) {
                int cc = (c + rot) & 7;
                float4 v = buf4[(t << 3) | cc];
                a[2 * cc]     = make_float2(v.x, v.y);
                a[2 * cc + 1] = make_float2(v.z, v.w);
            }
        }
        apply_gate<1>(a, cr[cb + 11], sr[cb + 11]);
        apply_gate<2>(a, cr[cb + 10], sr[cb + 10]);
        apply_gate<4>(a, cr[cb + 9],  sr[cb + 9]);
        apply_gate<8>(a, cr[cb + 8],  sr[cb + 8]);
        #pragma unroll
        for (int c = 0; c < 8; ++c) {
            int cc = (c + rot) & 7;
            buf4[(t << 3) | cc] =
                make_float4(a[2 * cc].x, a[2 * cc].y, a[2 * cc + 1].x, a[2 * cc + 1].y);
        }
        __syncthreads();

        // ---- sweep 2: gates on bits p=4..7 (qubits 7..4) ----
        {
            const int base2 = ((t >> 4) << 8) | (t & 15);   // m = (hi<<8)|(j<<4)|lo
            #pragma unroll
            for (int j = 0; j < 16; ++j) a[j] = buf[base2 | (j << 4)];
            apply_gate<1>(a, cr[cb + 7], sr[cb + 7]);
            apply_gate<2>(a, cr[cb + 6], sr[cb + 6]);
            apply_gate<4>(a, cr[cb + 5], sr[cb + 5]);
            apply_gate<8>(a, cr[cb + 4], sr[cb + 4]);
            #pragma unroll
            for (int j = 0; j < 16; ++j) buf[base2 | (j << 4)] = a[j];
        }
        __syncthreads();

        // ---- sweep 3: gates on bits p=8..11 (qubits 3..0), CNOT perm fused ----
        #pragma unroll
        for (int j = 0; j < 16; ++j) a[j] = buf[(j << 8) | t];
        apply_gate<1>(a, cr[cb + 3], sr[cb + 3]);
        apply_gate<2>(a, cr[cb + 2], sr[cb + 2]);
        apply_gate<4>(a, cr[cb + 1], sr[cb + 1]);
        apply_gate<8>(a, cr[cb + 0], sr[cb + 0]);
        if (d < DEPTH - 1) {
            #pragma unroll
            for (int j = 0; j < 16; ++j)
                buf[igray12((j << 8) | t)] = a[j];   // bijective, conflict-free
            __syncthreads();
        }
    }

    // ---- Z expectations directly from registers (final perm applied to index) ----
    float z[NQ];
    #pragma unroll
    for (int q = 0; q < NQ; ++q) z[q] = 0.0f;
    #pragma unroll
    for (int j = 0; j < 16; ++j) {
        const int dst = igray12((j << 8) | t);
        const float pr = a[j].x * a[j].x + a[j].y * a[j].y;
        #pragma unroll
        for (int q = 0; q < NQ; ++q)
            z[q] += ((dst >> (NQ - 1 - q)) & 1) ? -pr : pr;
    }
    #pragma unroll
    for (int q = 0; q < NQ; ++q) {
        #pragma unroll
        for (int off = 32; off > 0; off >>= 1)
            z[q] += __shfl_down(z[q], off, 64);
    }
    const int wave = t >> 6, lane = t & 63;
    if (lane == 0) {
        #pragma unroll
        for (int q = 0; q < NQ; ++q) zred[wave][q] = z[q];
    }
    __syncthreads();
    if (t < NQ) {
        out[b * NQ + t] = zred[0][t] + zred[1][t] + zred[2][t] + zred[3][t];
    }
}

extern "C" void kernel_launch(void* const* d_in, const int* in_sizes, int n_in,
                              void* d_out, int out_size, void* d_ws, size_t ws_size,
                              hipStream_t stream) {
    const float* x   = (const float*)d_in[0];
    const float* rys = (const float*)d_in[1];
    // d_in[2] (cnot_params) is unused by the reference — CNOT takes no params.
    float* out = (float*)d_out;
    qsim_kernel<<<512, BLK, 0, stream>>>(x, rys, out);
}

// Round 3
// 22.050 us; speedup vs baseline: 5.1363x; 5.1363x over previous
//
#include <hip/hip_runtime.h>

#define NQ 12
#define DIM 4096          // 2^12 amplitudes
#define DEPTH 4
#define BLK 256
#define RSTR 18           // padded row stride in float2 (16 amps + 2 pad)
#define LSLOTS (256 * RSTR)

// inverse Gray code on 12 bits: bit p of result = XOR of bits >= p of v.
// This is the whole CNOT chain CNOT(0,1)...CNOT(10,11) as one permutation:
// new_state[igray12(src)] = old_state[src]. Linear over GF(2).
__device__ __forceinline__ int igray12(int v) {
    v ^= v >> 1;
    v ^= v >> 2;
    v ^= v >> 4;
    v ^= v >> 8;
    return v & (DIM - 1);
}

// padded LDS slot of amplitude m
__device__ __forceinline__ int lslot(int m) {
    return RSTR * (m >> 4) + (m & 15);
}

// RY gate on local subcube bit PB (compile-time => all register indices static)
template<int PB>
__device__ __forceinline__ void apply_gate(float2 (&a)[16], float c, float s) {
    #pragma unroll
    for (int j0 = 0; j0 < 16; ++j0) {
        if (j0 & PB) continue;
        const int j1 = j0 | PB;
        float2 a0 = a[j0], a1 = a[j1];
        a[j0] = make_float2(c * a0.x - s * a1.x, c * a0.y - s * a1.y);
        a[j1] = make_float2(s * a0.x + c * a1.x, s * a0.y + c * a1.y);
    }
}

__global__ __launch_bounds__(BLK, 2)
void qsim_kernel(const float* __restrict__ x,
                 const float* __restrict__ rys,
                 float* __restrict__ out) {
    __shared__ __align__(16) float2 buf[LSLOTS];     // 36 KB padded state
    __shared__ float cr[DEPTH * NQ], sr[DEPTH * NQ]; // RY cos/sin (shared)
    __shared__ float cxs[NQ], sxs[NQ];               // RX cos/sin (per batch)
    __shared__ float zred[4][NQ];

    const int b = blockIdx.x;
    const int t = threadIdx.x;

    if (t < DEPTH * NQ) {
        float th = 0.5f * rys[t];
        cr[t] = cosf(th);
        sr[t] = sinf(th);
    } else if (t >= 64 && t < 64 + NQ) {
        int q = t - 64;
        float th = 0.5f * x[b * NQ + q];
        cxs[q] = cosf(th);
        sxs[q] = sinf(th);
    }
    __syncthreads();

    float2 a[16];                       // the thread's 16 amplitudes (registers)
    float4* buf4 = reinterpret_cast<float4*>(buf);   // row stride 9 float4

    // ---- initial product state, built directly in sweep-1 register layout ----
    // m = (t<<4) | j ; amp(m) = prod_p(bit_p ? sin : cos)[qubit 11-p] * (-i)^popc(m)
    {
        float base = 1.0f;
        #pragma unroll
        for (int p = 4; p < NQ; ++p)
            base *= ((t >> (p - 4)) & 1) ? sxs[NQ - 1 - p] : cxs[NQ - 1 - p];
        const int pch = __popc(t);
        #pragma unroll
        for (int j = 0; j < 16; ++j) {
            float mag = base;
            #pragma unroll
            for (int p = 0; p < 4; ++p)
                mag *= ((j >> p) & 1) ? sxs[NQ - 1 - p] : cxs[NQ - 1 - p];
            int pc = (pch + __popc(j)) & 3;
            float2 v;
            v.x = (pc == 0) ? mag : ((pc == 2) ? -mag : 0.0f);
            v.y = (pc == 1) ? -mag : ((pc == 3) ? mag : 0.0f);
            a[j] = v;
        }
    }

    for (int d = 0; d < DEPTH; ++d) {
        const int cb = d * NQ;

        // ---- sweep 1: gates on bits p=0..3 (qubits 11..8) ----
        if (d > 0) {
            #pragma unroll
            for (int c = 0; c < 8; ++c) {
                float4 v = buf4[9 * t + c];
                a[2 * c]     = make_float2(v.x, v.y);
                a[2 * c + 1] = make_float2(v.z, v.w);
            }
        }
        apply_gate<1>(a, cr[cb + 11], sr[cb + 11]);
        apply_gate<2>(a, cr[cb + 10], sr[cb + 10]);
        apply_gate<4>(a, cr[cb + 9],  sr[cb + 9]);
        apply_gate<8>(a, cr[cb + 8],  sr[cb + 8]);
        #pragma unroll
        for (int c = 0; c < 8; ++c) {
            buf4[9 * t + c] =
                make_float4(a[2 * c].x, a[2 * c].y, a[2 * c + 1].x, a[2 * c + 1].y);
        }
        __syncthreads();

        // ---- sweep 2: gates on bits p=4..7 (qubits 7..4) ----
        {
            const int base2 = 288 * (t >> 4) + (t & 15);   // L((hi2<<8)|lo)
            #pragma unroll
            for (int j = 0; j < 16; ++j) a[j] = buf[base2 + RSTR * j];
            apply_gate<1>(a, cr[cb + 7], sr[cb + 7]);
            apply_gate<2>(a, cr[cb + 6], sr[cb + 6]);
            apply_gate<4>(a, cr[cb + 5], sr[cb + 5]);
            apply_gate<8>(a, cr[cb + 4], sr[cb + 4]);
            #pragma unroll
            for (int j = 0; j < 16; ++j) buf[base2 + RSTR * j] = a[j];
        }
        __syncthreads();

        // ---- sweep 3: gates on bits p=8..11 (qubits 3..0), CNOT perm fused ----
        {
            const int base3 = RSTR * (t >> 4) + (t & 15);  // L(t)
            #pragma unroll
            for (int j = 0; j < 16; ++j) a[j] = buf[base3 + 288 * j];
            apply_gate<1>(a, cr[cb + 3], sr[cb + 3]);
            apply_gate<2>(a, cr[cb + 2], sr[cb + 2]);
            apply_gate<4>(a, cr[cb + 1], sr[cb + 1]);
            apply_gate<8>(a, cr[cb + 0], sr[cb + 0]);
            if (d < DEPTH - 1) {
                #pragma unroll
                for (int j = 0; j < 16; ++j)
                    buf[lslot(igray12((j << 8) | t))] = a[j];  // bijective
                __syncthreads();
            }
        }
    }

    // ---- Z expectations directly from registers (final perm applied to index) ----
    float z[NQ];
    #pragma unroll
    for (int q = 0; q < NQ; ++q) z[q] = 0.0f;
    #pragma unroll
    for (int j = 0; j < 16; ++j) {
        const int dst = igray12((j << 8) | t);
        const float pr = a[j].x * a[j].x + a[j].y * a[j].y;
        #pragma unroll
        for (int q = 0; q < NQ; ++q)
            z[q] += ((dst >> (NQ - 1 - q)) & 1) ? -pr : pr;
    }
    #pragma unroll
    for (int q = 0; q < NQ; ++q) {
        #pragma unroll
        for (int off = 32; off > 0; off >>= 1)
            z[q] += __shfl_down(z[q], off, 64);
    }
    const int wave = t >> 6, lane = t & 63;
    if (lane == 0) {
        #pragma unroll
        for (int q = 0; q < NQ; ++q) zred[wave][q] = z[q];
    }
    __syncthreads();
    if (t < NQ) {
        out[b * NQ + t] = zred[0][t] + zred[1][t] + zred[2][t] + zred[3][t];
    }
}

extern "C" void kernel_launch(void* const* d_in, const int* in_sizes, int n_in,
                              void* d_out, int out_size, void* d_ws, size_t ws_size,
                              hipStream_t stream) {
    const float* x   = (const float*)d_in[0];
    const float* rys = (const float*)d_in[1];
    // d_in[2] (cnot_params) is unused by the reference — CNOT takes no params.
    float* out = (float*)d_out;
    qsim_kernel<<<512, BLK, 0, stream>>>(x, rys, out);
}

// Round 5
// 21.689 us; speedup vs baseline: 5.2216x; 1.0166x over previous
//
#include <hip/hip_runtime.h>

#define NQ 12
#define DIM 4096          // 2^12 amplitudes
#define DEPTH 4
#define BLK 512           // 8 amps/thread -> 8 waves/block, 16 waves/CU

// inverse Gray code on 12 bits == the CNOT chain CNOT(0,1)..CNOT(10,11):
// new_state[igray12(src)] = old_state[src]. GF(2)-linear.
__host__ __device__ constexpr int igray12c(int v) {
    v ^= v >> 1; v ^= v >> 2; v ^= v >> 4; v ^= v >> 8;
    return v & (DIM - 1);
}

// physical LDS slot of amplitude m (float2 units). GF(2)-linear XOR swizzle:
// minimal bank occupancy for all four sweep patterns AND the fused igray store.
__host__ __device__ constexpr int pslotc(int m) {
    int row = m >> 3, off = m & 7;
    int prow = row ^ ((row >> 3) & 7);
    int poff = off ^ ((row ^ (row >> 3)) & 6);
    return (prow << 3) | poff;
}

// RY gate on local subcube bit PB (compile-time => static register indices)
template<int PB>
__device__ __forceinline__ void gate8(float2 (&a)[8], float c, float s) {
    #pragma unroll
    for (int j0 = 0; j0 < 8; ++j0) {
        if (j0 & PB) continue;
        const int j1 = j0 | PB;
        float2 a0 = a[j0], a1 = a[j1];
        a[j0] = make_float2(c * a0.x - s * a1.x, c * a0.y - s * a1.y);
        a[j1] = make_float2(s * a0.x + c * a1.x, s * a0.y + c * a1.y);
    }
}

__global__ __launch_bounds__(BLK, 4)   // 4 waves/EU hint; LDS caps us at 2 blk/CU
void qsim_kernel(const float* __restrict__ x,
                 const float* __restrict__ rys,
                 float* __restrict__ out) {
    // double-buffered state: sweep-D's permuted store writes the OTHER buffer,
    // eliminating the cross-wave load/store race (no extra barriers needed).
    __shared__ __align__(16) float2 buf[2][DIM];     // 64 KB
    __shared__ float cr[DEPTH * NQ], sr[DEPTH * NQ]; // RY cos/sin
    __shared__ float cxs[NQ], sxs[NQ];               // RX cos/sin (per batch)
    __shared__ float zred[8][NQ];

    const int b = blockIdx.x;
    const int t = threadIdx.x;      // 9 bits

    if (t < DEPTH * NQ) {
        float th = 0.5f * rys[t];
        cr[t] = cosf(th); sr[t] = sinf(th);
    } else if (t >= 64 && t < 64 + NQ) {
        int q = t - 64;
        float th = 0.5f * x[b * NQ + q];
        cxs[q] = cosf(th); sxs[q] = sinf(th);
    }
    __syncthreads();

    // ---- loop-invariant physical address bases (swizzle pre-applied) ----
    // sweep A (m = t<<3 | j): float4 chunk index = qA ^ c
    const int prowA = t ^ ((t >> 3) & 7);
    const int qA = (prowA << 2) | (((t ^ (t >> 3)) & 6) >> 1);
    // sweep B (m = h<<6 | j<<3 | lo): slot = baseB ^ ((j<<3)|(j&6))
    const int hB = t >> 3, loB = t & 7;
    const int baseB = (hB << 6) | ((hB & 7) << 3) | (loB ^ (hB & 6));
    // sweep C (m = h3<<9 | j<<6 | lo6): slot = baseC ^ ((j<<6)|(j<<3)|(j&6))
    const int h3 = t >> 6, lo6 = t & 63;
    const int baseC = (h3 << 9) | (lo6 & 56) | ((lo6 & 7) ^ ((lo6 >> 3) & 6));
    // sweep D (m = j<<9 | t): slot = baseD + (j<<9)
    const int baseD = (((t >> 3) ^ (t >> 6)) << 3)
                    | ((t & 7) ^ ((t >> 3) & 6) ^ ((t >> 6) & 6));
    // fused CNOT store: slot = pG ^ pslotc(igray12c(j<<9))   (both linear)
    const int G  = igray12c(t);
    const int pG = pslotc(G);

    float2 a[8];                                     // thread's 8 amplitudes

    // ---- initial product state in sweep-A register layout ----
    // m = (t<<3)|j ; amp = prod_p(bit ? sin : cos)[qubit 11-p] * (-i)^popc(m)
    {
        float base = 1.0f;
        #pragma unroll
        for (int p = 3; p < NQ; ++p)
            base *= ((t >> (p - 3)) & 1) ? sxs[NQ - 1 - p] : cxs[NQ - 1 - p];
        const int pch = __popc(t);
        #pragma unroll
        for (int j = 0; j < 8; ++j) {
            float mag = base;
            #pragma unroll
            for (int p = 0; p < 3; ++p)
                mag *= ((j >> p) & 1) ? sxs[NQ - 1 - p] : cxs[NQ - 1 - p];
            int pc = (pch + __popc(j)) & 3;
            a[j] = make_float2((pc == 0) ? mag : ((pc == 2) ? -mag : 0.0f),
                               (pc == 1) ? -mag : ((pc == 3) ? mag : 0.0f));
        }
    }

    #pragma unroll
    for (int d = 0; d < DEPTH; ++d) {
        const int cb = d * NQ;
        float2* bp = buf[d & 1];           // current buffer (compile-time per iter)
        float2* bq = buf[(d & 1) ^ 1];     // permutation target
        float4* bp4 = reinterpret_cast<float4*>(bp);

        // ---- sweep A: bits 0..2 (qubits 11,10,9) ----
        if (d > 0) {
            #pragma unroll
            for (int c = 0; c < 4; ++c) {
                float4 v = bp4[qA ^ c];
                a[2 * c]     = make_float2(v.x, v.y);
                a[2 * c + 1] = make_float2(v.z, v.w);
            }
        }
        gate8<1>(a, cr[cb + 11], sr[cb + 11]);
        gate8<2>(a, cr[cb + 10], sr[cb + 10]);
        gate8<4>(a, cr[cb + 9],  sr[cb + 9]);
        #pragma unroll
        for (int c = 0; c < 4; ++c)
            bp4[qA ^ c] = make_float4(a[2 * c].x, a[2 * c].y,
                                      a[2 * c + 1].x, a[2 * c + 1].y);
        __syncthreads();

        // ---- sweep B: bits 3..5 (qubits 8,7,6) ----
        #pragma unroll
        for (int j = 0; j < 8; ++j) a[j] = bp[baseB ^ ((j << 3) | (j & 6))];
        gate8<1>(a, cr[cb + 8], sr[cb + 8]);
        gate8<2>(a, cr[cb + 7], sr[cb + 7]);
        gate8<4>(a, cr[cb + 6], sr[cb + 6]);
        #pragma unroll
        for (int j = 0; j < 8; ++j) bp[baseB ^ ((j << 3) | (j & 6))] = a[j];
        __syncthreads();

        // ---- sweep C: bits 6..8 (qubits 5,4,3) ----
        #pragma unroll
        for (int j = 0; j < 8; ++j)
            a[j] = bp[baseC ^ ((j << 6) | (j << 3) | (j & 6))];
        gate8<1>(a, cr[cb + 5], sr[cb + 5]);
        gate8<2>(a, cr[cb + 4], sr[cb + 4]);
        gate8<4>(a, cr[cb + 3], sr[cb + 3]);
        #pragma unroll
        for (int j = 0; j < 8; ++j)
            bp[baseC ^ ((j << 6) | (j << 3) | (j & 6))] = a[j];
        __syncthreads();

        // ---- sweep D: bits 9..11 (qubits 2,1,0), CNOT perm fused in store ----
        #pragma unroll
        for (int j = 0; j < 8; ++j) a[j] = bp[baseD + (j << 9)];
        gate8<1>(a, cr[cb + 2], sr[cb + 2]);
        gate8<2>(a, cr[cb + 1], sr[cb + 1]);
        gate8<4>(a, cr[cb + 0], sr[cb + 0]);
        if (d < DEPTH - 1) {
            #pragma unroll
            for (int j = 0; j < 8; ++j)
                bq[pG ^ pslotc(igray12c(j << 9))] = a[j];  // disjoint buffer: no race
            __syncthreads();
        }
    }

    // ---- Z expectations: dst = G ^ cg_j, signs factor per-bit ----
    float zacc[NQ];
    #pragma unroll
    for (int q = 0; q < NQ; ++q) zacc[q] = 0.0f;
    #pragma unroll
    for (int j = 0; j < 8; ++j) {
        const int cg = igray12c(j << 9);                // compile-time
        const float pr = a[j].x * a[j].x + a[j].y * a[j].y;
        #pragma unroll
        for (int q = 0; q < NQ; ++q)
            zacc[q] += ((cg >> (NQ - 1 - q)) & 1) ? -pr : pr;
    }
    #pragma unroll
    for (int q = 0; q < NQ; ++q) {
        float v = ((G >> (NQ - 1 - q)) & 1) ? -zacc[q] : zacc[q];
        #pragma unroll
        for (int off = 32; off > 0; off >>= 1)
            v += __shfl_down(v, off, 64);
        zacc[q] = v;
    }
    const int wave = t >> 6, lane = t & 63;
    if (lane == 0) {
        #pragma unroll
        for (int q = 0; q < NQ; ++q) zred[wave][q] = zacc[q];
    }
    __syncthreads();
    if (t < NQ) {
        float s = 0.0f;
        #pragma unroll
        for (int w = 0; w < 8; ++w) s += zred[w][t];
        out[b * NQ + t] = s;
    }
}

extern "C" void kernel_launch(void* const* d_in, const int* in_sizes, int n_in,
                              void* d_out, int out_size, void* d_ws, size_t ws_size,
                              hipStream_t stream) {
    const float* x   = (const float*)d_in[0];
    const float* rys = (const float*)d_in[1];
    // d_in[2] (cnot_params) unused by the reference — CNOT takes no params.
    float* out = (float*)d_out;
    qsim_kernel<<<512, BLK, 0, stream>>>(x, rys, out);
}

// Round 6
// 21.661 us; speedup vs baseline: 5.2285x; 1.0013x over previous
//
#include <hip/hip_runtime.h>

#define NQ 12
#define DIM 4096          // 2^12 amplitudes
#define DEPTH 4
#define BLK 512           // 8 amps/thread -> 8 waves/block, 16 waves/CU

// inverse Gray code on 12 bits == the CNOT chain CNOT(0,1)..CNOT(10,11):
// new_state[igray12(src)] = old_state[src]. GF(2)-linear.
__host__ __device__ constexpr int igray12c(int v) {
    v ^= v >> 1; v ^= v >> 2; v ^= v >> 4; v ^= v >> 8;
    return v & (DIM - 1);
}

// physical LDS slot of amplitude m (float2 units). GF(2)-linear XOR swizzle:
// minimal bank occupancy for all four sweep patterns AND the fused igray store.
// Note: slot bits 9-11 == m bits 9-11, so waves own disjoint 512-amp regions
// during sweeps A/B/C (m bits 9-11 == wave id there) -> those sweeps need no
// cross-wave barrier, only same-wave LDS ordering (s_waitcnt lgkmcnt(0)).
__host__ __device__ constexpr int pslotc(int m) {
    int row = m >> 3, off = m & 7;
    int prow = row ^ ((row >> 3) & 7);
    int poff = off ^ ((row ^ (row >> 3)) & 6);
    return (prow << 3) | poff;
}

// same-wave LDS write->read ordering: drain lgkmcnt so this wave's ds_writes
// are committed before its subsequent ds_reads; "memory" stops compiler
// reordering. Cross-wave visibility is NOT needed (wave-exclusive regions).
#define WAVE_LDS_FENCE() asm volatile("s_waitcnt lgkmcnt(0)" ::: "memory")

// RY gate on local subcube bit PB (compile-time => static register indices)
template<int PB>
__device__ __forceinline__ void gate8(float2 (&a)[8], float c, float s) {
    #pragma unroll
    for (int j0 = 0; j0 < 8; ++j0) {
        if (j0 & PB) continue;
        const int j1 = j0 | PB;
        float2 a0 = a[j0], a1 = a[j1];
        a[j0] = make_float2(c * a0.x - s * a1.x, c * a0.y - s * a1.y);
        a[j1] = make_float2(s * a0.x + c * a1.x, s * a0.y + c * a1.y);
    }
}

__global__ __launch_bounds__(BLK, 4)   // 4 waves/EU hint; LDS caps us at 2 blk/CU
void qsim_kernel(const float* __restrict__ x,
                 const float* __restrict__ rys,
                 float* __restrict__ out) {
    // double-buffered state: sweep-D's permuted store writes the OTHER buffer,
    // eliminating the cross-wave load/store race without an extra barrier.
    __shared__ __align__(16) float2 buf[2][DIM];     // 64 KB
    __shared__ float cr[DEPTH * NQ], sr[DEPTH * NQ]; // RY cos/sin
    __shared__ float cxs[NQ], sxs[NQ];               // RX cos/sin (per batch)
    __shared__ float zred[8][NQ];

    const int b = blockIdx.x;
    const int t = threadIdx.x;      // 9 bits

    if (t < DEPTH * NQ) {
        float th = 0.5f * rys[t];
        cr[t] = cosf(th); sr[t] = sinf(th);
    } else if (t >= 64 && t < 64 + NQ) {
        int q = t - 64;
        float th = 0.5f * x[b * NQ + q];
        cxs[q] = cosf(th); sxs[q] = sinf(th);
    }
    __syncthreads();

    // ---- loop-invariant physical address bases (swizzle pre-applied) ----
    // sweep A (m = t<<3 | j): float4 chunk index = qA ^ c
    const int prowA = t ^ ((t >> 3) & 7);
    const int qA = (prowA << 2) | (((t ^ (t >> 3)) & 6) >> 1);
    // sweep B (m = h<<6 | j<<3 | lo): slot = baseB ^ ((j<<3)|(j&6))
    const int hB = t >> 3, loB = t & 7;
    const int baseB = (hB << 6) | ((hB & 7) << 3) | (loB ^ (hB & 6));
    // sweep C (m = h3<<9 | j<<6 | lo6): slot = baseC ^ ((j<<6)|(j<<3)|(j&6))
    const int h3 = t >> 6, lo6 = t & 63;
    const int baseC = (h3 << 9) | (lo6 & 56) | ((lo6 & 7) ^ ((lo6 >> 3) & 6));
    // sweep D (m = j<<9 | t): slot = baseD + (j<<9)
    const int baseD = (((t >> 3) ^ (t >> 6)) << 3)
                    | ((t & 7) ^ ((t >> 3) & 6) ^ ((t >> 6) & 6));
    // fused CNOT store: slot = pG ^ pslotc(igray12c(j<<9))   (both linear)
    const int G  = igray12c(t);
    const int pG = pslotc(G);

    float2 a[8];                                     // thread's 8 amplitudes

    // ---- initial product state in sweep-A register layout ----
    // m = (t<<3)|j ; amp = prod_p(bit ? sin : cos)[qubit 11-p] * (-i)^popc(m)
    {
        float base = 1.0f;
        #pragma unroll
        for (int p = 3; p < NQ; ++p)
            base *= ((t >> (p - 3)) & 1) ? sxs[NQ - 1 - p] : cxs[NQ - 1 - p];
        const int pch = __popc(t);
        #pragma unroll
        for (int j = 0; j < 8; ++j) {
            float mag = base;
            #pragma unroll
            for (int p = 0; p < 3; ++p)
                mag *= ((j >> p) & 1) ? sxs[NQ - 1 - p] : cxs[NQ - 1 - p];
            int pc = (pch + __popc(j)) & 3;
            a[j] = make_float2((pc == 0) ? mag : ((pc == 2) ? -mag : 0.0f),
                               (pc == 1) ? -mag : ((pc == 3) ? mag : 0.0f));
        }
    }

    #pragma unroll
    for (int d = 0; d < DEPTH; ++d) {
        const int cb = d * NQ;
        float2* bp = buf[d & 1];           // current buffer (compile-time per iter)
        float2* bq = buf[(d & 1) ^ 1];     // permutation target
        float4* bp4 = reinterpret_cast<float4*>(bp);

        // ---- sweep A: bits 0..2 (qubits 11,10,9) — wave-local region ----
        if (d > 0) {
            #pragma unroll
            for (int c = 0; c < 4; ++c) {
                float4 v = bp4[qA ^ c];
                a[2 * c]     = make_float2(v.x, v.y);
                a[2 * c + 1] = make_float2(v.z, v.w);
            }
        }
        gate8<1>(a, cr[cb + 11], sr[cb + 11]);
        gate8<2>(a, cr[cb + 10], sr[cb + 10]);
        gate8<4>(a, cr[cb + 9],  sr[cb + 9]);
        #pragma unroll
        for (int c = 0; c < 4; ++c)
            bp4[qA ^ c] = make_float4(a[2 * c].x, a[2 * c].y,
                                      a[2 * c + 1].x, a[2 * c + 1].y);
        WAVE_LDS_FENCE();                  // intra-wave regroup: no barrier

        // ---- sweep B: bits 3..5 (qubits 8,7,6) — wave-local region ----
        #pragma unroll
        for (int j = 0; j < 8; ++j) a[j] = bp[baseB ^ ((j << 3) | (j & 6))];
        gate8<1>(a, cr[cb + 8], sr[cb + 8]);
        gate8<2>(a, cr[cb + 7], sr[cb + 7]);
        gate8<4>(a, cr[cb + 6], sr[cb + 6]);
        #pragma unroll
        for (int j = 0; j < 8; ++j) bp[baseB ^ ((j << 3) | (j & 6))] = a[j];
        WAVE_LDS_FENCE();                  // intra-wave regroup: no barrier

        // ---- sweep C: bits 6..8 (qubits 5,4,3) — wave-local region ----
        #pragma unroll
        for (int j = 0; j < 8; ++j)
            a[j] = bp[baseC ^ ((j << 6) | (j << 3) | (j & 6))];
        gate8<1>(a, cr[cb + 5], sr[cb + 5]);
        gate8<2>(a, cr[cb + 4], sr[cb + 4]);
        gate8<4>(a, cr[cb + 3], sr[cb + 3]);
        #pragma unroll
        for (int j = 0; j < 8; ++j)
            bp[baseC ^ ((j << 6) | (j << 3) | (j & 6))] = a[j];
        __syncthreads();                   // C->D moves amps across waves

        // ---- sweep D: bits 9..11 (qubits 2,1,0), CNOT perm fused in store ----
        #pragma unroll
        for (int j = 0; j < 8; ++j) a[j] = bp[baseD + (j << 9)];
        gate8<1>(a, cr[cb + 2], sr[cb + 2]);
        gate8<2>(a, cr[cb + 1], sr[cb + 1]);
        gate8<4>(a, cr[cb + 0], sr[cb + 0]);
        if (d < DEPTH - 1) {
            #pragma unroll
            for (int j = 0; j < 8; ++j)
                bq[pG ^ pslotc(igray12c(j << 9))] = a[j];  // disjoint buffer
            __syncthreads();               // perm is cross-wave
        }
    }

    // ---- Z expectations: dst = G ^ cg_j, signs factor per-bit ----
    float zacc[NQ];
    #pragma unroll
    for (int q = 0; q < NQ; ++q) zacc[q] = 0.0f;
    #pragma unroll
    for (int j = 0; j < 8; ++j) {
        const int cg = igray12c(j << 9);                // compile-time
        const float pr = a[j].x * a[j].x + a[j].y * a[j].y;
        #pragma unroll
        for (int q = 0; q < NQ; ++q)
            zacc[q] += ((cg >> (NQ - 1 - q)) & 1) ? -pr : pr;
    }
    #pragma unroll
    for (int q = 0; q < NQ; ++q) {
        float v = ((G >> (NQ - 1 - q)) & 1) ? -zacc[q] : zacc[q];
        #pragma unroll
        for (int off = 32; off > 0; off >>= 1)
            v += __shfl_down(v, off, 64);
        zacc[q] = v;
    }
    const int wave = t >> 6, lane = t & 63;
    if (lane == 0) {
        #pragma unroll
        for (int q = 0; q < NQ; ++q) zred[wave][q] = zacc[q];
    }
    __syncthreads();
    if (t < NQ) {
        float s = 0.0f;
        #pragma unroll
        for (int w = 0; w < 8; ++w) s += zred[w][t];
        out[b * NQ + t] = s;
    }
}

extern "C" void kernel_launch(void* const* d_in, const int* in_sizes, int n_in,
                              void* d_out, int out_size, void* d_ws, size_t ws_size,
                              hipStream_t stream) {
    const float* x   = (const float*)d_in[0];
    const float* rys = (const float*)d_in[1];
    // d_in[2] (cnot_params) unused by the reference — CNOT takes no params.
    float* out = (float*)d_out;
    qsim_kernel<<<512, BLK, 0, stream>>>(x, rys, out);
}

// Round 7
// 17.621 us; speedup vs baseline: 6.4270x; 1.2292x over previous
//
#include <hip/hip_runtime.h>

#define NQ 12
#define DIM 4096
#define BLK 512

typedef float v2f __attribute__((ext_vector_type(2)));

// inverse Gray code == CNOT chain: new_state[igray(src)] = old_state[src]. Linear.
__host__ __device__ constexpr int igray12c(int v) {
    v ^= v >> 1; v ^= v >> 2; v ^= v >> 4; v ^= v >> 8;
    return v & (DIM - 1);
}
// LDS slot swizzle (GF(2)-linear, bijective): rank-4 bank-pair spread for all
// sweep patterns (A, B, C16 loads) and all sigma∘igray perm stores.
__host__ __device__ constexpr int sigc(int v) { return v ^ ((v >> 4) & 0xF); }

// C16 register-bit scatter per layer: S1={6,7,8,9} S2={6,7,10,11} S3={6,8,9,10}
template<int D> __host__ __device__ constexpr int scat(int j) {
    return D == 1 ? (j << 6)
         : D == 2 ? (((j & 3) << 6) | ((j >> 2) << 10))
                  : (((j & 1) << 6) | (((j >> 1) & 7) << 8));
}

#define WAVE_LDS_FENCE() asm volatile("s_waitcnt lgkmcnt(0)" ::: "memory")

__device__ __forceinline__ v2f cmul(v2f a, v2f b) {
    v2f r; r.x = a.x * b.x - a.y * b.y; r.y = a.x * b.y + a.y * b.x; return r;
}
// RY on a pair: a0 = |bit=0>, a1 = |bit=1>
__device__ __forceinline__ void gate_pair(v2f& a0, v2f& a1, float c, float s) {
    v2f t0 = a0, t1 = a1;
    a0 = c * t0 - s * t1;
    a1 = s * t0 + c * t1;
}
template<int PB, int N>
__device__ __forceinline__ void gateN(v2f (&a)[N], float c, float s) {
    #pragma unroll
    for (int j0 = 0; j0 < N; ++j0) {
        if (j0 & PB) continue;
        gate_pair(a[j0], a[j0 | PB], c, s);
    }
}

// wave64 sum on the VALU pipe (DPP row ops), result valid in lane 63
__device__ __forceinline__ float wave64_sum(float v) {
    v += __int_as_float(__builtin_amdgcn_update_dpp(0, __float_as_int(v), 0x111, 0xf, 0xf, true));
    v += __int_as_float(__builtin_amdgcn_update_dpp(0, __float_as_int(v), 0x112, 0xf, 0xf, true));
    v += __int_as_float(__builtin_amdgcn_update_dpp(0, __float_as_int(v), 0x114, 0xf, 0xf, true));
    v += __int_as_float(__builtin_amdgcn_update_dpp(0, __float_as_int(v), 0x118, 0xf, 0xf, true));
    v += __int_as_float(__builtin_amdgcn_update_dpp(0, __float_as_int(v), 0x142, 0xa, 0xf, false));
    v += __int_as_float(__builtin_amdgcn_update_dpp(0, __float_as_int(v), 0x143, 0xc, 0xf, false));
    return v;
}

// sweeps A (bits 0-2 = qubits 11,10,9) and B (bits 3-5 = qubits 8,7,6),
// in-place, wave-local (slot bits 9-11 == m bits 9-11 == wave id)
__device__ __forceinline__ void sweepAB(v2f* bp, int t, const float* cr,
                                        const float* sr, int d12) {
    const int sbA = sigc(t << 3);
    {
        v2f a[8];
        #pragma unroll
        for (int j = 0; j < 8; ++j) a[j] = bp[sbA ^ j];
        gateN<1>(a, cr[d12 + 11], sr[d12 + 11]);
        gateN<2>(a, cr[d12 + 10], sr[d12 + 10]);
        gateN<4>(a, cr[d12 + 9],  sr[d12 + 9]);
        #pragma unroll
        for (int j = 0; j < 8; ++j) bp[sbA ^ j] = a[j];
    }
    WAVE_LDS_FENCE();
    const int sbB = sigc(((t >> 3) << 6) | (t & 7));
    {
        v2f a[8];
        #pragma unroll
        for (int j = 0; j < 8; ++j) a[j] = bp[sbB ^ ((j << 3) | (j >> 1))];
        gateN<1>(a, cr[d12 + 8], sr[d12 + 8]);
        gateN<2>(a, cr[d12 + 7], sr[d12 + 7]);
        gateN<4>(a, cr[d12 + 6], sr[d12 + 6]);
        #pragma unroll
        for (int j = 0; j < 8; ++j) bp[sbB ^ ((j << 3) | (j >> 1))] = a[j];
    }
}

// C16: load 16 amps (reg bits = S_d), apply this layer's 4 gates. Returns m_base.
template<int D>
__device__ __forceinline__ int c16_load_gates(const v2f* bp, int t,
                                              const float* cr, const float* sr,
                                              v2f (&a)[16]) {
    int mb;
    if constexpr (D == 1)      mb = (((t >> 6) & 3) << 10) | (t & 63);
    else if constexpr (D == 2) mb = (((t >> 6) & 3) << 8) | (t & 63);
    else                       mb = (((t >> 7) & 1) << 11) | (((t >> 6) & 1) << 7) | (t & 63);
    const int sb = sigc(mb);
    #pragma unroll
    for (int j = 0; j < 16; ++j) a[j] = bp[sb ^ sigc(scat<D>(j))];
    const int d12 = D * NQ;
    if constexpr (D == 1) {        // bits 6,7,8,9 -> qubits 5,4,3,2
        gateN<1>(a, cr[d12 + 5], sr[d12 + 5]);
        gateN<2>(a, cr[d12 + 4], sr[d12 + 4]);
        gateN<4>(a, cr[d12 + 3], sr[d12 + 3]);
        gateN<8>(a, cr[d12 + 2], sr[d12 + 2]);
    } else if constexpr (D == 2) { // bits 6,7,10,11 -> qubits 5,4,1,0
        gateN<1>(a, cr[d12 + 5], sr[d12 + 5]);
        gateN<2>(a, cr[d12 + 4], sr[d12 + 4]);
        gateN<4>(a, cr[d12 + 1], sr[d12 + 1]);
        gateN<8>(a, cr[d12 + 0], sr[d12 + 0]);
    } else {                       // bits 6,8,9,10 -> qubits 5,3,2,1
        gateN<1>(a, cr[d12 + 5], sr[d12 + 5]);
        gateN<2>(a, cr[d12 + 3], sr[d12 + 3]);
        gateN<4>(a, cr[d12 + 2], sr[d12 + 2]);
        gateN<8>(a, cr[d12 + 1], sr[d12 + 1]);
    }
    return mb;
}

__global__ __launch_bounds__(BLK, 4)
void qsim_kernel(const float* __restrict__ x,
                 const float* __restrict__ rys,
                 float* __restrict__ out) {
    __shared__ v2f buf[2][DIM];            // 64 KB double-buffered state
    __shared__ float cr[4 * NQ], sr[4 * NQ];
    __shared__ v2f fac[NQ][2];             // init per-qubit complex factors
    __shared__ float zred[4][NQ];

    const int b = blockIdx.x;
    const int t = threadIdx.x;             // 9 bits

    if (t < 4 * NQ) {
        float th = 0.5f * rys[t];
        cr[t] = cosf(th); sr[t] = sinf(th);
    }
    if (t >= 64 && t < 64 + NQ) {
        int q = t - 64;
        float xh = 0.5f * x[b * NQ + q];
        float cx = cosf(xh), sx = sinf(xh);
        float th = 0.5f * rys[q];          // layer-0 RY absorbed into init
        float c0 = cosf(th), s0 = sinf(th);
        int p = NQ - 1 - q;                // bit position of qubit q
        fac[p][0] = v2f{c0 * cx,  s0 * sx};   // RY*RX|0>, bit=0 component
        fac[p][1] = v2f{s0 * cx, -c0 * sx};   // bit=1 component
    }
    __syncthreads();

    v2f* b0 = buf[0];
    v2f* b1 = buf[1];

    // ================= layer 0: product init + perm0 + pre-gate L1{b10,b11} ====
    {
        v2f a[8];                          // m = (j<<9) | t
        v2f P = fac[0][t & 1];
        #pragma unroll
        for (int p = 1; p < 9; ++p) P = cmul(P, fac[p][(t >> p) & 1]);
        #pragma unroll
        for (int j = 0; j < 8; ++j) {
            v2f H = cmul(cmul(fac[9][j & 1], fac[10][(j >> 1) & 1]), fac[11][(j >> 2) & 1]);
            a[j] = cmul(P, H);
        }
        // post-perm labels n=igray(m): bit10 pairs j^3 (val j1^j2), bit11 pairs j^6 (val j2); no flip
        {   float c = cr[NQ + 1], s = sr[NQ + 1];     // layer1 qubit1 (bit10)
            gate_pair(a[0], a[3], c, s); gate_pair(a[1], a[2], c, s);
            gate_pair(a[7], a[4], c, s); gate_pair(a[6], a[5], c, s); }
        {   float c = cr[NQ + 0], s = sr[NQ + 0];     // layer1 qubit0 (bit11)
            gate_pair(a[0], a[6], c, s); gate_pair(a[1], a[7], c, s);
            gate_pair(a[2], a[4], c, s); gate_pair(a[3], a[5], c, s); }
        const int pb = sigc(igray12c(t));
        #pragma unroll
        for (int j = 0; j < 8; ++j)
            b1[pb ^ sigc(igray12c(j << 9))] = a[j];
    }
    __syncthreads();

    // ================= layer 1 ===============================================
    sweepAB(b1, t, cr, sr, 1 * NQ);
    __syncthreads();
    if (t < 256) {
        v2f a[16];
        const int mb = c16_load_gates<1>(b1, t, cr, sr, a);
        // pre-gate layer2 on n=igray(m): bit8 (q3) pairs j^6 val j2^j3;
        // bit9 (q2) pairs j^12 val j3; flip = t6^t7 (wave-uniform)
        const float fsg = (((t >> 6) ^ (t >> 7)) & 1) ? -1.0f : 1.0f;
        {   float c = cr[2 * NQ + 3], s = fsg * sr[2 * NQ + 3];
            gate_pair(a[0], a[6], c, s);   gate_pair(a[1], a[7], c, s);
            gate_pair(a[2], a[4], c, s);   gate_pair(a[3], a[5], c, s);
            gate_pair(a[14], a[8], c, s);  gate_pair(a[15], a[9], c, s);
            gate_pair(a[12], a[10], c, s); gate_pair(a[13], a[11], c, s); }
        {   float c = cr[2 * NQ + 2], s = fsg * sr[2 * NQ + 2];
            gate_pair(a[0], a[12], c, s);  gate_pair(a[1], a[13], c, s);
            gate_pair(a[2], a[14], c, s);  gate_pair(a[3], a[15], c, s);
            gate_pair(a[4], a[8], c, s);   gate_pair(a[5], a[9], c, s);
            gate_pair(a[6], a[10], c, s);  gate_pair(a[7], a[11], c, s); }
        const int pb = sigc(igray12c(mb));
        #pragma unroll
        for (int j = 0; j < 16; ++j)
            b0[pb ^ sigc(igray12c(scat<1>(j)))] = a[j];
    }
    __syncthreads();

    // ================= layer 2 ===============================================
    sweepAB(b0, t, cr, sr, 2 * NQ);
    __syncthreads();
    if (t < 256) {
        v2f a[16];
        const int mb = c16_load_gates<2>(b0, t, cr, sr, a);
        // pre-gate layer3: bit7 (q4) pairs j^3 val j1^j2^j3, flip t6^t7;
        // bit11 (q0) pairs j^12 val j3, no flip
        const float fsg = (((t >> 6) ^ (t >> 7)) & 1) ? -1.0f : 1.0f;
        {   float c = cr[3 * NQ + 4], s = fsg * sr[3 * NQ + 4];
            gate_pair(a[0], a[3], c, s);   gate_pair(a[1], a[2], c, s);
            gate_pair(a[7], a[4], c, s);   gate_pair(a[6], a[5], c, s);
            gate_pair(a[11], a[8], c, s);  gate_pair(a[10], a[9], c, s);
            gate_pair(a[12], a[15], c, s); gate_pair(a[13], a[14], c, s); }
        {   float c = cr[3 * NQ + 0], s = sr[3 * NQ + 0];
            gate_pair(a[0], a[12], c, s);  gate_pair(a[1], a[13], c, s);
            gate_pair(a[2], a[14], c, s);  gate_pair(a[3], a[15], c, s);
            gate_pair(a[4], a[8], c, s);   gate_pair(a[5], a[9], c, s);
            gate_pair(a[6], a[10], c, s);  gate_pair(a[7], a[11], c, s); }
        const int pb = sigc(igray12c(mb));
        #pragma unroll
        for (int j = 0; j < 16; ++j)
            b1[pb ^ sigc(igray12c(scat<2>(j)))] = a[j];
    }
    __syncthreads();

    // ================= layer 3 + Z ===========================================
    sweepAB(b1, t, cr, sr, 3 * NQ);
    __syncthreads();
    if (t < 256) {
        v2f a[16];
        const int mb = c16_load_gates<3>(b1, t, cr, sr, a);
        // Z directly from registers; labels n = igray(mb) ^ igray(scat3(j))
        float zacc[NQ];
        #pragma unroll
        for (int q = 0; q < NQ; ++q) zacc[q] = 0.0f;
        #pragma unroll
        for (int j = 0; j < 16; ++j) {
            const int ns = igray12c(scat<3>(j));   // compile-time sign part
            const float pr = a[j].x * a[j].x + a[j].y * a[j].y;
            #pragma unroll
            for (int q = 0; q < NQ; ++q)
                zacc[q] += ((ns >> (NQ - 1 - q)) & 1) ? -pr : pr;
        }
        const int rt = igray12c(mb);               // runtime sign part
        #pragma unroll
        for (int q = 0; q < NQ; ++q) {
            float v = ((rt >> (NQ - 1 - q)) & 1) ? -zacc[q] : zacc[q];
            v = wave64_sum(v);
            if ((t & 63) == 63) zred[t >> 6][q] = v;
        }
    }
    __syncthreads();
    if (t < NQ)
        out[b * NQ + t] = zred[0][t] + zred[1][t] + zred[2][t] + zred[3][t];
}

extern "C" void kernel_launch(void* const* d_in, const int* in_sizes, int n_in,
                              void* d_out, int out_size, void* d_ws, size_t ws_size,
                              hipStream_t stream) {
    const float* x   = (const float*)d_in[0];
    const float* rys = (const float*)d_in[1];
    // d_in[2] (cnot_params) unused by the reference — CNOT takes no params.
    float* out = (float*)d_out;
    qsim_kernel<<<512, BLK, 0, stream>>>(x, rys, out);
}